// Round 3
// baseline (3325.135 us; speedup 1.0000x reference)
//
#include <hip/hip_runtime.h>
#include <hip/hip_bf16.h>
#include <math.h>

#define B_ 2
#define S_ 1024
#define H_ 512
#define FF_ 2048
#define V_ 50304
#define L_ 6
#define EPS_ 1e-5f

typedef __attribute__((ext_vector_type(8))) short short8_t;
typedef __attribute__((ext_vector_type(4))) float f32x4;

__device__ __forceinline__ unsigned short f2bf(float f) {
    union { float f; unsigned int u; } x; x.f = f;
    unsigned int r = x.u + 0x7fffu + ((x.u >> 16) & 1u);   // round-nearest-even
    return (unsigned short)(r >> 16);
}

// ---------------------------------------------------------------- embed
__global__ __launch_bounds__(128) void embed_kernel(const int* __restrict__ ids,
                                                    const float* __restrict__ table,
                                                    float* __restrict__ h) {
    int row = blockIdx.x;                 // B*S rows
    int t = threadIdx.x;                  // 128 threads, 4 floats each
    int id = ids[row];
    const float4* src = reinterpret_cast<const float4*>(table + (size_t)id * H_);
    float4* dst = reinterpret_cast<float4*>(h + (size_t)row * H_);
    dst[t] = src[t];
}

// ---------------------------------------------------------------- layernorm
// one wave per row (H=512 -> 8 floats/lane)
__global__ __launch_bounds__(256) void ln_kernel(const float* __restrict__ in,
                                                 const float* __restrict__ g,
                                                 const float* __restrict__ b,
                                                 float* __restrict__ out) {
    int row = blockIdx.x * 4 + (threadIdx.x >> 6);
    int lane = threadIdx.x & 63;
    const float* r = in + (size_t)row * H_;
    float4 v0 = *reinterpret_cast<const float4*>(r + lane * 8);
    float4 v1 = *reinterpret_cast<const float4*>(r + lane * 8 + 4);
    float s = v0.x + v0.y + v0.z + v0.w + v1.x + v1.y + v1.z + v1.w;
    float q = v0.x*v0.x + v0.y*v0.y + v0.z*v0.z + v0.w*v0.w
            + v1.x*v1.x + v1.y*v1.y + v1.z*v1.z + v1.w*v1.w;
#pragma unroll
    for (int off = 1; off < 64; off <<= 1) {
        s += __shfl_xor(s, off);
        q += __shfl_xor(q, off);
    }
    float mean = s * (1.0f / H_);
    float var  = q * (1.0f / H_) - mean * mean;
    float rs = rsqrtf(var + EPS_);

    float4 g0 = *reinterpret_cast<const float4*>(g + lane * 8);
    float4 g1 = *reinterpret_cast<const float4*>(g + lane * 8 + 4);
    float4 b0 = *reinterpret_cast<const float4*>(b + lane * 8);
    float4 b1 = *reinterpret_cast<const float4*>(b + lane * 8 + 4);
    float4 o0, o1;
    o0.x = (v0.x - mean) * rs * g0.x + b0.x;
    o0.y = (v0.y - mean) * rs * g0.y + b0.y;
    o0.z = (v0.z - mean) * rs * g0.z + b0.z;
    o0.w = (v0.w - mean) * rs * g0.w + b0.w;
    o1.x = (v1.x - mean) * rs * g1.x + b1.x;
    o1.y = (v1.y - mean) * rs * g1.y + b1.y;
    o1.z = (v1.z - mean) * rs * g1.z + b1.z;
    o1.w = (v1.w - mean) * rs * g1.w + b1.w;
    float* w = out + (size_t)row * H_;
    *reinterpret_cast<float4*>(w + lane * 8) = o0;
    *reinterpret_cast<float4*>(w + lane * 8 + 4) = o1;
}

// ---------------------------------------------------------------- attention shortcut
// ka_scan collapses to broadcasting A[i] = v0 (value at position 0). So the whole
// attention layer output is, for every position s of batch b:
//   attn[b,s,:] = (x[b,0,:] @ Wv^T + bv) @ Wd^T + bd      (two 512x512 matvecs)
__global__ __launch_bounds__(512) void attn_shortcut_kernel(const float* __restrict__ x,
                                                            const float* __restrict__ Wv,
                                                            const float* __restrict__ bv,
                                                            const float* __restrict__ Wd,
                                                            const float* __restrict__ bd,
                                                            float* __restrict__ attn_c) {
    int b = blockIdx.x;
    int t = threadIdx.x;                  // 512 threads
    __shared__ float x0[H_];
    __shared__ float v0[H_];
    x0[t] = x[(size_t)b * S_ * H_ + t];
    __syncthreads();
    float acc = bv[t];
    const float4* w = reinterpret_cast<const float4*>(Wv + (size_t)t * H_);
#pragma unroll 4
    for (int k = 0; k < H_ / 4; ++k) {
        float4 wv = w[k];
        acc += x0[4*k+0] * wv.x + x0[4*k+1] * wv.y + x0[4*k+2] * wv.z + x0[4*k+3] * wv.w;
    }
    v0[t] = acc;
    __syncthreads();
    float acc2 = bd[t];
    const float4* w2 = reinterpret_cast<const float4*>(Wd + (size_t)t * H_);
#pragma unroll 4
    for (int k = 0; k < H_ / 4; ++k) {
        float4 wv = w2[k];
        acc2 += v0[4*k+0] * wv.x + v0[4*k+1] * wv.y + v0[4*k+2] * wv.z + v0[4*k+3] * wv.w;
    }
    attn_c[b * H_ + t] = acc2;
}

// ---------------------------------------------------------------- MFMA GEMM (bf16 in, fp32 acc, NT)
// out[m,n] = sum_k X[m,k] * W[n,k]  (+ epilogue)
// fp32 sources are cast to bf16 on the fly while staging to LDS.
// mode 0: (+bias if non-null)            -> logits
// mode 1: gelu(acc + bias)               -> fc1
// mode 2: resid + attn_c + (acc + bias)  -> fc2 + residual merge
//
// Tile: 128x128 per block, 4 waves in 2x2, each wave 64x64 (4x4 frags of 16x16).
// BK=64 bf16 per stage. LDS rows padded 64->72 elems (144B = 9*16B): keeps
// ds_read_b128 16B-aligned and spreads the stride-128 conflict to 2-way (free).
#define BM 128
#define BN 128
#define BKB 64
#define LDP 72

__global__ __launch_bounds__(256) void gemm_mfma_nt(const float* __restrict__ X,
                                                    const float* __restrict__ W,
                                                    const float* __restrict__ bias,
                                                    const float* __restrict__ resid,
                                                    const float* __restrict__ attn_c,
                                                    float* __restrict__ out,
                                                    int M, int N, int K, int mode) {
    __shared__ __align__(16) unsigned short As[BM * LDP];
    __shared__ __align__(16) unsigned short Bs[BN * LDP];
    const int t = threadIdx.x;
    const int lane = t & 63;
    const int w = t >> 6;
    const int wr = w >> 1, wc = w & 1;
    const int bm0 = blockIdx.x * BM;
    const int bn0 = blockIdx.y * BN;
    const int l15 = lane & 15;
    const int lg  = lane >> 4;            // 0..3

    f32x4 acc[4][4] = {};

    for (int k0 = 0; k0 < K; k0 += BKB) {
        // stage A (X) and B (W): 128 rows x 64 cols each, fp32 -> bf16
#pragma unroll
        for (int i = 0; i < 8; ++i) {
            int f4  = t + i * 256;         // float4 index, 0..2047
            int row = f4 >> 4;             // 16 float4 per row
            int c4  = f4 & 15;
            float4 va = *reinterpret_cast<const float4*>(X + (size_t)(bm0 + row) * K + k0 + c4 * 4);
            float4 vb = *reinterpret_cast<const float4*>(W + (size_t)(bn0 + row) * K + k0 + c4 * 4);
            ushort4 ua, ub;
            ua.x = f2bf(va.x); ua.y = f2bf(va.y); ua.z = f2bf(va.z); ua.w = f2bf(va.w);
            ub.x = f2bf(vb.x); ub.y = f2bf(vb.y); ub.z = f2bf(vb.z); ub.w = f2bf(vb.w);
            *reinterpret_cast<ushort4*>(&As[row * LDP + c4 * 4]) = ua;
            *reinterpret_cast<ushort4*>(&Bs[row * LDP + c4 * 4]) = ub;
        }
        __syncthreads();
#pragma unroll
        for (int kk = 0; kk < 2; ++kk) {
            short8_t a[4], b[4];
#pragma unroll
            for (int i = 0; i < 4; ++i)
                a[i] = *reinterpret_cast<const short8_t*>(&As[(wr * 64 + i * 16 + l15) * LDP + kk * 32 + lg * 8]);
#pragma unroll
            for (int j = 0; j < 4; ++j)
                b[j] = *reinterpret_cast<const short8_t*>(&Bs[(wc * 64 + j * 16 + l15) * LDP + kk * 32 + lg * 8]);
#pragma unroll
            for (int i = 0; i < 4; ++i)
#pragma unroll
                for (int j = 0; j < 4; ++j)
                    acc[i][j] = __builtin_amdgcn_mfma_f32_16x16x32_bf16(a[i], b[j], acc[i][j], 0, 0, 0);
        }
        __syncthreads();
    }

    // epilogue: C/D layout (verified): col = lane&15, row = (lane>>4)*4 + reg
#pragma unroll
    for (int j = 0; j < 4; ++j) {
        int n = bn0 + wc * 64 + j * 16 + l15;
        float bias_n = bias ? bias[n] : 0.0f;
#pragma unroll
        for (int i = 0; i < 4; ++i) {
#pragma unroll
            for (int r = 0; r < 4; ++r) {
                int m = bm0 + wr * 64 + i * 16 + lg * 4 + r;
                float v = acc[i][j][r] + bias_n;
                if (mode == 1) {
                    v = 0.5f * v * (1.0f + erff(v * 0.70710678118654752f));
                } else if (mode == 2) {
                    int bb = m >> 10;      // S_=1024 rows per batch
                    v += resid[(size_t)m * N + n] + attn_c[bb * H_ + n];
                }
                out[(size_t)m * N + n] = v;
            }
        }
    }
}

// ---------------------------------------------------------------- launch
extern "C" void kernel_launch(void* const* d_in, const int* in_sizes, int n_in,
                              void* d_out, int out_size, void* d_ws, size_t ws_size,
                              hipStream_t stream) {
    const int*   ids     = (const int*)d_in[0];
    const float* table   = (const float*)d_in[1];
    const float* qkv_w   = (const float*)d_in[2];
    const float* qkv_b   = (const float*)d_in[3];
    const float* dense_w = (const float*)d_in[4];
    const float* dense_b = (const float*)d_in[5];
    const float* fc1_w   = (const float*)d_in[6];
    const float* fc1_b   = (const float*)d_in[7];
    const float* fc2_w   = (const float*)d_in[8];
    const float* fc2_b   = (const float*)d_in[9];
    const float* ln_g    = (const float*)d_in[10];
    const float* ln_b    = (const float*)d_in[11];
    const float* fln_g   = (const float*)d_in[12];
    const float* fln_b   = (const float*)d_in[13];
    const float* out_w   = (const float*)d_in[14];
    float* logits = (float*)d_out;

    float* ws     = (float*)d_ws;
    float* h      = ws;                       // 1M floats
    float* x      = ws + (1 << 20);           // 1M floats
    float* attn_c = ws + (2 << 20);           // 1024 floats
    float* mlp1   = logits;                   // borrow d_out (16.8MB of 412MB); fully overwritten at the end

    const int M = B_ * S_;                    // 2048

    embed_kernel<<<M, 128, 0, stream>>>(ids, table, h);

    for (int l = 0; l < L_; ++l) {
        ln_kernel<<<M / 4, 256, 0, stream>>>(h, ln_g + l * H_, ln_b + l * H_, x);

        attn_shortcut_kernel<<<B_, 512, 0, stream>>>(
            x,
            qkv_w + (size_t)l * 3 * H_ * H_ + (size_t)2 * H_ * H_,   // v-slice rows [1024:1536)
            qkv_b + l * 3 * H_ + 2 * H_,
            dense_w + (size_t)l * H_ * H_,
            dense_b + l * H_,
            attn_c);

        dim3 g1(M / BM, FF_ / BN);
        gemm_mfma_nt<<<g1, 256, 0, stream>>>(x, fc1_w + (size_t)l * FF_ * H_, fc1_b + l * FF_,
                                             nullptr, nullptr, mlp1, M, FF_, H_, 1);

        dim3 g2(M / BM, H_ / BN);
        gemm_mfma_nt<<<g2, 256, 0, stream>>>(mlp1, fc2_w + (size_t)l * H_ * FF_, fc2_b + l * H_,
                                             h, attn_c, h, M, H_, FF_, 2);
    }

    ln_kernel<<<M / 4, 256, 0, stream>>>(h, fln_g, fln_b, x);

    dim3 g3(M / BM, V_ / BN);
    gemm_mfma_nt<<<g3, 256, 0, stream>>>(x, out_w, nullptr, nullptr, nullptr, logits,
                                         M, V_, H_, 0);
}